// Round 11
// baseline (259.460 us; speedup 1.0000x reference)
//
#include <hip/hip_runtime.h>
#include <hip/hip_bf16.h>

#define NHID 128
#define NGRAPH 512
#define NCLS 10

typedef __attribute__((ext_vector_type(8))) short bf16x8;
typedef __attribute__((ext_vector_type(4))) float f32x4;
typedef __attribute__((ext_vector_type(4))) unsigned int u32x4;

// order-preserving float<->uint encoding for atomicMax-based segment max
__device__ inline unsigned int fenc(float f) {
    unsigned int u = __float_as_uint(f);
    return (u & 0x80000000u) ? ~u : (u | 0x80000000u);
}
__device__ inline float fdec(unsigned int u) {
    u = (u & 0x80000000u) ? (u & 0x7fffffffu) : ~u;
    return __uint_as_float(u);
}
// f32 -> bf16 round-to-nearest-even (finite inputs)
__device__ inline unsigned short f2bf(float f) {
    unsigned int u = __float_as_uint(f);
    return (unsigned short)((u + 0x7fffu + ((u >> 16) & 1u)) >> 16);
}
__device__ inline unsigned int packbf(float lo, float hi) {
    return (unsigned)f2bf(lo) | ((unsigned)f2bf(hi) << 16);
}

// merged front kernel: deg atomics | x->bf16 | W transpose | keys zero
__global__ void k_front(const int* __restrict__ dst, int* __restrict__ cnt, int E, int degB,
                        const float* __restrict__ x, unsigned int* __restrict__ xb, int n8, int xB,
                        const float* __restrict__ W1, const float* __restrict__ W2,
                        const float* __restrict__ W3, unsigned short* __restrict__ Wt,
                        unsigned int* __restrict__ keys) {
    int b = blockIdx.x;
    if (b < degB) {
        int e = b * 256 + threadIdx.x;
        if (e < E) atomicAdd(&cnt[dst[e]], 1);
    } else if (b < degB + xB) {
        int i = (b - degB) * 256 + threadIdx.x;
        if (i < n8) {
            const float* p = x + (size_t)i * 8;
            f32x4 a = *reinterpret_cast<const f32x4*>(p);
            f32x4 c = *reinterpret_cast<const f32x4*>(p + 4);
            u32x4 o;
            o[0] = packbf(a[0], a[1]);
            o[1] = packbf(a[2], a[3]);
            o[2] = packbf(c[0], c[1]);
            o[3] = packbf(c[2], c[3]);
            *reinterpret_cast<u32x4*>(xb + (size_t)i * 4) = o;
        }
    } else if (b < degB + xB + 192) {
        int idx = (b - degB - xB) * 256 + threadIdx.x;   // < 3*16384
        int l = idx >> 14;
        int r = idx & 16383;
        const float* W = (l == 0) ? W1 : (l == 1) ? W2 : W3;
        int c = r & 127, k = r >> 7;
        Wt[l * 16384 + c * NHID + k] = f2bf(W[k * NHID + c]);
    } else {
        int i = (b - degB - xB - 192) * 256 + threadIdx.x;
        if (i < NGRAPH * NHID) keys[i] = 0u;
    }
}

// phase 1: per-block (1024-wide) scan of cnt; store chunk-local EXCLUSIVE
// prefix at rowptr[i]; block totals into bsum; dinv as a free rider.
__global__ __launch_bounds__(1024) void k_scan1(const int* __restrict__ cnt,
        float* __restrict__ dinv, int* __restrict__ rowptr,
        int* __restrict__ bsum, int N) {
    __shared__ int lds[1024];
    int t = threadIdx.x;
    int i = blockIdx.x * 1024 + t;
    int v = (i < N) ? cnt[i] : 0;
    if (i < N) dinv[i] = rsqrtf((float)v + 1.0f);
    lds[t] = v;
    __syncthreads();
    for (int off = 1; off < 1024; off <<= 1) {
        int x = (t >= off) ? lds[t - off] : 0;
        __syncthreads();
        lds[t] += x;
        __syncthreads();
    }
    if (i < N) rowptr[i] = lds[t] - v;     // exclusive within chunk
    if (t == 1023) bsum[blockIdx.x] = lds[1023];
}

// phase 2: exclusive scan of nb block sums (nb <= 1024), in place
__global__ __launch_bounds__(1024) void k_scan2(int* __restrict__ bsum, int nb) {
    __shared__ int lds[1024];
    int t = threadIdx.x;
    int v = (t < nb) ? bsum[t] : 0;
    lds[t] = v;
    __syncthreads();
    for (int off = 1; off < 1024; off <<= 1) {
        int x = (t >= off) ? lds[t - off] : 0;
        __syncthreads();
        lds[t] += x;
        __syncthreads();
    }
    if (t < nb) bsum[t] = lds[t] - v;
}

// build CSR src list (4B/edge); norms are computed in the gather
__global__ void k_fill(const int* __restrict__ src, const int* __restrict__ dst,
                       const int* __restrict__ rowptr, const int* __restrict__ bsum,
                       int* __restrict__ cursor, int* __restrict__ csr_src, int E) {
    int e = blockIdx.x * blockDim.x + threadIdx.x;
    if (e >= E) return;
    int s = src[e], d = dst[e];
    int pos = rowptr[d] + bsum[d >> 10] + atomicAdd(&cursor[d], 1);
    csr_src[pos] = s;
}

__device__ inline void fma8(const u32x4& u, float nw, float* a) {
#pragma unroll
    for (int q = 0; q < 4; ++q) {
        a[2 * q]     = fmaf(nw, __uint_as_float(u[q] << 16), a[2 * q]);
        a[2 * q + 1] = fmaf(nw, __uint_as_float(u[q] & 0xffff0000u), a[2 * q + 1]);
    }
}

// shared gather phase: one wave per node -> bf16 row in lds[wv][]
__device__ inline void gather_row(const unsigned int* __restrict__ Hin,
        const int* __restrict__ csr_src, const int* __restrict__ rowptr,
        const int* __restrict__ bsum, const int* __restrict__ cnt,
        const float* __restrict__ dinv, unsigned int (*lds)[68],
        int w, int wv, int g, int l16, int N) {
    if (w < N) {
        float diw = dinv[w];
        u32x4 us = reinterpret_cast<const u32x4*>(Hin + (size_t)w * (NHID / 2))[l16];
        float a[8];
#pragma unroll
        for (int e = 0; e < 8; ++e) a[e] = 0.f;
        int beg = rowptr[w] + bsum[w >> 10];
        int deg = cnt[w];
        int end = beg + deg;
        int trips = (deg + 15) >> 4;
        int j = beg + g;
        for (int t = 0; t < trips; ++t, j += 16) {
            int s0 = w, s1 = w, s2 = w, s3 = w;
            if (j < end)      s0 = csr_src[j];
            if (j + 4 < end)  s1 = csr_src[j + 4];
            if (j + 8 < end)  s2 = csr_src[j + 8];
            if (j + 12 < end) s3 = csr_src[j + 12];
            float n0 = (j < end)      ? dinv[s0] * diw : 0.f;
            float n1 = (j + 4 < end)  ? dinv[s1] * diw : 0.f;
            float n2 = (j + 8 < end)  ? dinv[s2] * diw : 0.f;
            float n3 = (j + 12 < end) ? dinv[s3] * diw : 0.f;
            u32x4 u0 = reinterpret_cast<const u32x4*>(Hin + (size_t)s0 * (NHID / 2))[l16];
            u32x4 u1 = reinterpret_cast<const u32x4*>(Hin + (size_t)s1 * (NHID / 2))[l16];
            u32x4 u2 = reinterpret_cast<const u32x4*>(Hin + (size_t)s2 * (NHID / 2))[l16];
            u32x4 u3 = reinterpret_cast<const u32x4*>(Hin + (size_t)s3 * (NHID / 2))[l16];
            fma8(u0, n0, a);
            fma8(u1, n1, a);
            fma8(u2, n2, a);
            fma8(u3, n3, a);
        }
        if (g == 0) fma8(us, diw * diw, a);
#pragma unroll
        for (int e = 0; e < 8; ++e) {
            a[e] += __shfl_xor(a[e], 16);
            a[e] += __shfl_xor(a[e], 32);
        }
        if (g == 0) {
            u32x4 o;
            o[0] = packbf(a[0], a[1]);
            o[1] = packbf(a[2], a[3]);
            o[2] = packbf(a[4], a[5]);
            o[3] = packbf(a[6], a[7]);
            *reinterpret_cast<u32x4*>(&lds[wv][l16 * 4]) = o;
        }
    } else if (g == 0) {
        u32x4 z = {0u, 0u, 0u, 0u};
        *reinterpret_cast<u32x4*>(&lds[wv][l16 * 4]) = z;
    }
}

// Fused aggregate+GEMM (layers 1-2): 512-thr block = 8 waves, one wave per
// node gather (8 nodes/block) -> LDS rows 0..7 (rows 8..15 zero-padded),
// barrier, then ALL 8 waves compute one 16-col MFMA tile each.
// 8-wave barrier granularity + 4 blocks/CU cuts slow-wave imbalance vs the
// 16-wave variant; waves never idle through the MFMA phase.
__global__ __launch_bounds__(512, 8) void k_agg_gemm(const unsigned int* __restrict__ Hin,
        const int* __restrict__ csr_src, const int* __restrict__ rowptr,
        const int* __restrict__ bsum, const int* __restrict__ cnt,
        const float* __restrict__ dinv, const unsigned short* __restrict__ Wt,
        const float* __restrict__ bias, unsigned short* __restrict__ Hout, int N) {
    __shared__ unsigned int lds[16][68];
    int wv = threadIdx.x >> 6;        // 0..7
    int lane = threadIdx.x & 63;
    int g = lane >> 4;
    int l16 = lane & 15;
    int n0 = blockIdx.x * 8;
    int w = n0 + wv;
    if (g == 1) {   // zero pad row wv+8 (parallel with gather's row write)
        u32x4 z = {0u, 0u, 0u, 0u};
        *reinterpret_cast<u32x4*>(&lds[wv + 8][l16 * 4]) = z;
    }
    gather_row(Hin, csr_src, rowptr, bsum, cnt, dinv, lds, w, wv, g, l16, N);
    __syncthreads();
    // wave wv computes output cols wv*16 .. wv*16+15 for rows 0..7
    int lr = l16;
    int kq = g;
    f32x4 acc = {0.f, 0.f, 0.f, 0.f};
#pragma unroll
    for (int kg = 0; kg < 4; ++kg) {
        bf16x8 af = *reinterpret_cast<const bf16x8*>(&lds[lr][kg * 16 + kq * 4]);
        bf16x8 bf = *reinterpret_cast<const bf16x8*>(
            Wt + (size_t)(wv * 16 + lr) * NHID + kg * 32 + kq * 8);
        acc = __builtin_amdgcn_mfma_f32_16x16x32_bf16(af, bf, acc, 0, 0, 0);
    }
    int c = wv * 16 + lr;
    float b = bias[c];
#pragma unroll
    for (int e = 0; e < 4; ++e) {
        int rr = kq * 4 + e;          // local row 0..15; 0..7 valid
        int r = n0 + rr;
        if (rr < 8 && r < N) {
            float v = fmaxf(acc[e] + b, 0.f);
            Hout[(size_t)r * NHID + c] = f2bf(v);
        }
    }
}

// Fused aggregate+GEMM+BN+segment-max (layer 3): same 8-node structure;
// epilogue applies bias+relu+BN, pre-reduces per-block segment max in LDS
// (8 rows, sorted batch -> small span), then flushes encoded atomicMax.
__global__ __launch_bounds__(512, 8) void k_agg_gemm_bn(const unsigned int* __restrict__ Hin,
        const int* __restrict__ csr_src, const int* __restrict__ rowptr,
        const int* __restrict__ bsum, const int* __restrict__ cnt,
        const float* __restrict__ dinv, const unsigned short* __restrict__ Wt,
        const float* __restrict__ bias, const int* __restrict__ batch,
        const float* __restrict__ gamma, const float* __restrict__ beta,
        const float* __restrict__ rmean, const float* __restrict__ rvar,
        unsigned int* __restrict__ keys, int N) {
    __shared__ unsigned int lds[16][68];
    __shared__ unsigned int smax[8][NHID];   // 4 KB, indexed by local segment
    __shared__ int bseg[8];
    int tid = threadIdx.x;
    int wv = tid >> 6;
    int lane = tid & 63;
    int g = lane >> 4;
    int l16 = lane & 15;
    int n0 = blockIdx.x * 8;
    for (int i = tid; i < 8 * NHID; i += 512) ((unsigned int*)smax)[i] = 0u;
    if (tid < 8) {
        int r = n0 + tid;
        bseg[tid] = batch[r < N ? r : N - 1];
    }
    if (g == 1) {
        u32x4 z = {0u, 0u, 0u, 0u};
        *reinterpret_cast<u32x4*>(&lds[wv + 8][l16 * 4]) = z;
    }
    int w = n0 + wv;
    gather_row(Hin, csr_src, rowptr, bsum, cnt, dinv, lds, w, wv, g, l16, N);
    __syncthreads();   // lds rows + smax init + bseg ready
    int lr = l16;
    int kq = g;
    f32x4 acc = {0.f, 0.f, 0.f, 0.f};
#pragma unroll
    for (int kg = 0; kg < 4; ++kg) {
        bf16x8 af = *reinterpret_cast<const bf16x8*>(&lds[lr][kg * 16 + kq * 4]);
        bf16x8 bf = *reinterpret_cast<const bf16x8*>(
            Wt + (size_t)(wv * 16 + lr) * NHID + kg * 32 + kq * 8);
        acc = __builtin_amdgcn_mfma_f32_16x16x32_bf16(af, bf, acc, 0, 0, 0);
    }
    int c = wv * 16 + lr;
    float b = bias[c];
    float sc = gamma[c] * rsqrtf(rvar[c] + 1e-5f);
    float sh = beta[c] - rmean[c] * sc;
    int glo = bseg[0];
#pragma unroll
    for (int e = 0; e < 4; ++e) {
        int rr = kq * 4 + e;              // local row 0..15; 0..7 valid
        if (rr < 8 && n0 + rr < N) {
            float v = fmaxf(acc[e] + b, 0.f);
            float y = fmaf(v, sc, sh);
            atomicMax(&smax[bseg[rr] - glo][c], fenc(y));
        }
    }
    __syncthreads();
    int last = N - 1 - n0;
    if (last > 7) last = 7;
    int span = bseg[last] - glo + 1;
    for (int i = tid; i < span * NHID; i += 512) {
        unsigned int v = ((unsigned int*)smax)[i];
        if (v) atomicMax(&keys[(size_t)(glo + (i >> 7)) * NHID + (i & 127)], v);
    }
}

// fused head: decode keys -> relu(G@lw1+lb1) -> relu(@lw2+lb2) -> @lw3+lb3
__global__ __launch_bounds__(128) void k_head(const unsigned int* __restrict__ keys,
        const float* __restrict__ lw1, const float* __restrict__ lb1,
        const float* __restrict__ lw2, const float* __restrict__ lb2,
        const float* __restrict__ lw3, const float* __restrict__ lb3,
        float* __restrict__ out) {
    __shared__ float g0[NHID], g1[NHID], g2[64];
    int r = blockIdx.x;
    int t = threadIdx.x;
    unsigned int u = keys[(size_t)r * NHID + t];
    g0[t] = (u == 0u) ? -3.0e38f : fdec(u);
    __syncthreads();
    float acc = lb1[t];
#pragma unroll 8
    for (int k = 0; k < NHID; ++k) acc = fmaf(g0[k], lw1[k * NHID + t], acc);
    g1[t] = fmaxf(acc, 0.f);
    __syncthreads();
    if (t < 64) {
        acc = lb2[t];
#pragma unroll 8
        for (int k = 0; k < NHID; ++k) acc = fmaf(g1[k], lw2[k * 64 + t], acc);
        g2[t] = fmaxf(acc, 0.f);
    }
    __syncthreads();
    if (t < NCLS) {
        acc = lb3[t];
#pragma unroll 8
        for (int k = 0; k < 64; ++k) acc = fmaf(g2[k], lw3[k * NCLS + t], acc);
        out[(size_t)r * NCLS + t] = acc;
    }
}

extern "C" void kernel_launch(void* const* d_in, const int* in_sizes, int n_in,
                              void* d_out, int out_size, void* d_ws, size_t ws_size,
                              hipStream_t stream) {
    const float* x     = (const float*)d_in[0];
    const int*   ei    = (const int*)d_in[1];
    const int*   batch = (const int*)d_in[2];
    const float* W1 = (const float*)d_in[3];
    const float* b1 = (const float*)d_in[4];
    const float* W2 = (const float*)d_in[5];
    const float* b2 = (const float*)d_in[6];
    const float* W3 = (const float*)d_in[7];
    const float* b3 = (const float*)d_in[8];
    const float* gamma = (const float*)d_in[9];
    const float* beta  = (const float*)d_in[10];
    const float* rmean = (const float*)d_in[11];
    const float* rvar  = (const float*)d_in[12];
    const float* lw1 = (const float*)d_in[13];
    const float* lb1 = (const float*)d_in[14];
    const float* lw2 = (const float*)d_in[15];
    const float* lb2 = (const float*)d_in[16];
    const float* lw3 = (const float*)d_in[17];
    const float* lb3 = (const float*)d_in[18];

    const int N = in_sizes[2];
    const int E = in_sizes[1] / 2;
    const int* src = ei;
    const int* dst = ei + E;

    char* ws = (char*)d_ws;
    size_t off = 0;
    auto alloc = [&](size_t bytes) {
        char* p = ws + off;
        off += (bytes + 255) & ~(size_t)255;
        return p;
    };
    int*   cnt     = (int*)  alloc((size_t)N * 8);     // cnt[N] + cursor[N], one memset
    int*   cursor  = cnt + N;
    int*   rowptr  = (int*)  alloc((size_t)N * 4);
    int*   bsum    = (int*)  alloc(1024 * 4);
    float* dinv    = (float*)alloc((size_t)N * 4);
    int*   csr_src = (int*)  alloc((size_t)E * 4);
    unsigned int* xb   = (unsigned int*)alloc((size_t)N * NHID * 2);
    unsigned int* Hb   = (unsigned int*)alloc((size_t)N * NHID * 2);
    unsigned int* H2   = (unsigned int*)alloc((size_t)N * NHID * 2);
    unsigned short* Wt = (unsigned short*)alloc((size_t)3 * NHID * NHID * 2);
    unsigned int* keys = (unsigned int*)alloc((size_t)NGRAPH * NHID * 4);
    (void)ws_size; (void)n_in; (void)out_size;

    hipMemsetAsync(cnt, 0, (size_t)N * 8, stream);

    int degB = (E + 255) / 256;
    int n8 = N * 16;
    int xB = (n8 + 255) / 256;
    int frontB = degB + xB + 192 + (NGRAPH * NHID + 255) / 256;
    k_front<<<frontB, 256, 0, stream>>>(dst, cnt, E, degB, x, xb, n8, xB,
                                        W1, W2, W3, Wt, keys);
    int nb1 = (N + 1023) / 1024;
    k_scan1<<<nb1, 1024, 0, stream>>>(cnt, dinv, rowptr, bsum, N);
    k_scan2<<<1, 1024, 0, stream>>>(bsum, nb1);
    k_fill<<<degB, 256, 0, stream>>>(src, dst, rowptr, bsum, cursor, csr_src, E);

    int fgb = (N + 7) / 8;                   // fused blocks (8 nodes each)
    // layer 1: xb -> Hb
    k_agg_gemm<<<fgb, 512, 0, stream>>>(xb, csr_src, rowptr, bsum, cnt, dinv,
                                        Wt, b1, (unsigned short*)Hb, N);
    // layer 2: Hb -> H2
    k_agg_gemm<<<fgb, 512, 0, stream>>>(Hb, csr_src, rowptr, bsum, cnt, dinv,
                                        Wt + 16384, b2, (unsigned short*)H2, N);
    // layer 3 fused: H2 -> keys (gemm+bn+segmax)
    k_agg_gemm_bn<<<fgb, 512, 0, stream>>>(H2, csr_src, rowptr, bsum, cnt, dinv,
                                           Wt + 32768, b3, batch, gamma, beta,
                                           rmean, rvar, keys, N);

    k_head<<<NGRAPH, 128, 0, stream>>>(keys, lw1, lb1, lw2, lb2, lw3, lb3, (float*)d_out);
}

// Round 12
// 230.773 us; speedup vs baseline: 1.1243x; 1.1243x over previous
//
#include <hip/hip_runtime.h>
#include <hip/hip_bf16.h>

#define NHID 128
#define NGRAPH 512
#define NCLS 10

typedef __attribute__((ext_vector_type(8))) short bf16x8;
typedef __attribute__((ext_vector_type(4))) float f32x4;
typedef __attribute__((ext_vector_type(4))) unsigned int u32x4;

// order-preserving float<->uint encoding for atomicMax-based segment max
__device__ inline unsigned int fenc(float f) {
    unsigned int u = __float_as_uint(f);
    return (u & 0x80000000u) ? ~u : (u | 0x80000000u);
}
__device__ inline float fdec(unsigned int u) {
    u = (u & 0x80000000u) ? (u & 0x7fffffffu) : ~u;
    return __uint_as_float(u);
}
// f32 -> bf16 round-to-nearest-even (finite inputs)
__device__ inline unsigned short f2bf(float f) {
    unsigned int u = __float_as_uint(f);
    return (unsigned short)((u + 0x7fffu + ((u >> 16) & 1u)) >> 16);
}
__device__ inline unsigned int packbf(float lo, float hi) {
    return (unsigned)f2bf(lo) | ((unsigned)f2bf(hi) << 16);
}

// merged front kernel: deg atomics | x->bf16 | W transpose | keys zero
__global__ void k_front(const int* __restrict__ dst, int* __restrict__ cnt, int E, int degB,
                        const float* __restrict__ x, unsigned int* __restrict__ xb, int n8, int xB,
                        const float* __restrict__ W1, const float* __restrict__ W2,
                        const float* __restrict__ W3, unsigned short* __restrict__ Wt,
                        unsigned int* __restrict__ keys) {
    int b = blockIdx.x;
    if (b < degB) {
        int e = b * 256 + threadIdx.x;
        if (e < E) atomicAdd(&cnt[dst[e]], 1);
    } else if (b < degB + xB) {
        int i = (b - degB) * 256 + threadIdx.x;
        if (i < n8) {
            const float* p = x + (size_t)i * 8;
            f32x4 a = *reinterpret_cast<const f32x4*>(p);
            f32x4 c = *reinterpret_cast<const f32x4*>(p + 4);
            u32x4 o;
            o[0] = packbf(a[0], a[1]);
            o[1] = packbf(a[2], a[3]);
            o[2] = packbf(c[0], c[1]);
            o[3] = packbf(c[2], c[3]);
            *reinterpret_cast<u32x4*>(xb + (size_t)i * 4) = o;
        }
    } else if (b < degB + xB + 192) {
        int idx = (b - degB - xB) * 256 + threadIdx.x;   // < 3*16384
        int l = idx >> 14;
        int r = idx & 16383;
        const float* W = (l == 0) ? W1 : (l == 1) ? W2 : W3;
        int c = r & 127, k = r >> 7;
        Wt[l * 16384 + c * NHID + k] = f2bf(W[k * NHID + c]);
    } else {
        int i = (b - degB - xB - 192) * 256 + threadIdx.x;
        if (i < NGRAPH * NHID) keys[i] = 0u;
    }
}

// phase 1: per-block (1024-wide) scan of cnt; store chunk-local EXCLUSIVE
// prefix at rowptr[i]; block totals into bsum; dinv as a free rider.
__global__ __launch_bounds__(1024) void k_scan1(const int* __restrict__ cnt,
        float* __restrict__ dinv, int* __restrict__ rowptr,
        int* __restrict__ bsum, int N) {
    __shared__ int lds[1024];
    int t = threadIdx.x;
    int i = blockIdx.x * 1024 + t;
    int v = (i < N) ? cnt[i] : 0;
    if (i < N) dinv[i] = rsqrtf((float)v + 1.0f);
    lds[t] = v;
    __syncthreads();
    for (int off = 1; off < 1024; off <<= 1) {
        int x = (t >= off) ? lds[t - off] : 0;
        __syncthreads();
        lds[t] += x;
        __syncthreads();
    }
    if (i < N) rowptr[i] = lds[t] - v;     // exclusive within chunk
    if (t == 1023) bsum[blockIdx.x] = lds[1023];
}

// phase 2: exclusive scan of nb block sums (nb <= 1024), in place
__global__ __launch_bounds__(1024) void k_scan2(int* __restrict__ bsum, int nb) {
    __shared__ int lds[1024];
    int t = threadIdx.x;
    int v = (t < nb) ? bsum[t] : 0;
    lds[t] = v;
    __syncthreads();
    for (int off = 1; off < 1024; off <<= 1) {
        int x = (t >= off) ? lds[t - off] : 0;
        __syncthreads();
        lds[t] += x;
        __syncthreads();
    }
    if (t < nb) bsum[t] = lds[t] - v;
}

// build CSR src list (4B/edge); norms are computed in the gather
__global__ void k_fill(const int* __restrict__ src, const int* __restrict__ dst,
                       const int* __restrict__ rowptr, const int* __restrict__ bsum,
                       int* __restrict__ cursor, int* __restrict__ csr_src, int E) {
    int e = blockIdx.x * blockDim.x + threadIdx.x;
    if (e >= E) return;
    int s = src[e], d = dst[e];
    int pos = rowptr[d] + bsum[d >> 10] + atomicAdd(&cursor[d], 1);
    csr_src[pos] = s;
}

__device__ inline void fma8(const u32x4& u, float nw, float* a) {
#pragma unroll
    for (int q = 0; q < 4; ++q) {
        a[2 * q]     = fmaf(nw, __uint_as_float(u[q] << 16), a[2 * q]);
        a[2 * q + 1] = fmaf(nw, __uint_as_float(u[q] & 0xffff0000u), a[2 * q + 1]);
    }
}

// shared gather phase: one wave gathers node w -> bf16 row in lds[row][]
__device__ inline void gather_row(const unsigned int* __restrict__ Hin,
        const int* __restrict__ csr_src, const int* __restrict__ rowptr,
        const int* __restrict__ bsum, const int* __restrict__ cnt,
        const float* __restrict__ dinv, unsigned int (*lds)[68],
        int w, int row, int g, int l16, int N) {
    if (w < N) {
        float diw = dinv[w];
        u32x4 us = reinterpret_cast<const u32x4*>(Hin + (size_t)w * (NHID / 2))[l16];
        float a[8];
#pragma unroll
        for (int e = 0; e < 8; ++e) a[e] = 0.f;
        int beg = rowptr[w] + bsum[w >> 10];
        int deg = cnt[w];
        int end = beg + deg;
        int trips = (deg + 15) >> 4;
        int j = beg + g;
        for (int t = 0; t < trips; ++t, j += 16) {
            int s0 = w, s1 = w, s2 = w, s3 = w;
            if (j < end)      s0 = csr_src[j];
            if (j + 4 < end)  s1 = csr_src[j + 4];
            if (j + 8 < end)  s2 = csr_src[j + 8];
            if (j + 12 < end) s3 = csr_src[j + 12];
            float n0 = (j < end)      ? dinv[s0] * diw : 0.f;
            float n1 = (j + 4 < end)  ? dinv[s1] * diw : 0.f;
            float n2 = (j + 8 < end)  ? dinv[s2] * diw : 0.f;
            float n3 = (j + 12 < end) ? dinv[s3] * diw : 0.f;
            u32x4 u0 = reinterpret_cast<const u32x4*>(Hin + (size_t)s0 * (NHID / 2))[l16];
            u32x4 u1 = reinterpret_cast<const u32x4*>(Hin + (size_t)s1 * (NHID / 2))[l16];
            u32x4 u2 = reinterpret_cast<const u32x4*>(Hin + (size_t)s2 * (NHID / 2))[l16];
            u32x4 u3 = reinterpret_cast<const u32x4*>(Hin + (size_t)s3 * (NHID / 2))[l16];
            fma8(u0, n0, a);
            fma8(u1, n1, a);
            fma8(u2, n2, a);
            fma8(u3, n3, a);
        }
        if (g == 0) fma8(us, diw * diw, a);
#pragma unroll
        for (int e = 0; e < 8; ++e) {
            a[e] += __shfl_xor(a[e], 16);
            a[e] += __shfl_xor(a[e], 32);
        }
        if (g == 0) {
            u32x4 o;
            o[0] = packbf(a[0], a[1]);
            o[1] = packbf(a[2], a[3]);
            o[2] = packbf(a[4], a[5]);
            o[3] = packbf(a[6], a[7]);
            *reinterpret_cast<u32x4*>(&lds[row][l16 * 4]) = o;
        }
    } else if (g == 0) {
        u32x4 z = {0u, 0u, 0u, 0u};
        *reinterpret_cast<u32x4*>(&lds[row][l16 * 4]) = z;
    }
}

// Fused aggregate+GEMM (layers 1-2): 1024-thr block = 16 waves, 32 NODES per
// block (wave wv gathers nodes 2wv, 2wv+1 -> LDS rows 2wv, 2wv+1). Pooling 2
// nodes/wave shrinks slowest-wave imbalance; MFMA phase has 16 tasks
// (8 col-tiles x 2 row-halves) so ALL 16 waves compute, 1 MFMA-op/node.
__global__ __launch_bounds__(1024) void k_agg_gemm(const unsigned int* __restrict__ Hin,
        const int* __restrict__ csr_src, const int* __restrict__ rowptr,
        const int* __restrict__ bsum, const int* __restrict__ cnt,
        const float* __restrict__ dinv, const unsigned short* __restrict__ Wt,
        const float* __restrict__ bias, unsigned short* __restrict__ Hout, int N) {
    __shared__ unsigned int lds[32][68];
    int wv = threadIdx.x >> 6;
    int lane = threadIdx.x & 63;
    int g = lane >> 4;
    int l16 = lane & 15;
    int n0 = blockIdx.x * 32;
    gather_row(Hin, csr_src, rowptr, bsum, cnt, dinv, lds, n0 + 2 * wv,     2 * wv,     g, l16, N);
    gather_row(Hin, csr_src, rowptr, bsum, cnt, dinv, lds, n0 + 2 * wv + 1, 2 * wv + 1, g, l16, N);
    __syncthreads();
    // wave wv: row-half rh (16 rows), col-tile ct (16 cols)
    int rh = wv >> 3;
    int ct = wv & 7;
    int lr = l16;
    int kq = g;
    f32x4 acc = {0.f, 0.f, 0.f, 0.f};
#pragma unroll
    for (int kg = 0; kg < 4; ++kg) {
        bf16x8 af = *reinterpret_cast<const bf16x8*>(&lds[rh * 16 + lr][kg * 16 + kq * 4]);
        bf16x8 bf = *reinterpret_cast<const bf16x8*>(
            Wt + (size_t)(ct * 16 + lr) * NHID + kg * 32 + kq * 8);
        acc = __builtin_amdgcn_mfma_f32_16x16x32_bf16(af, bf, acc, 0, 0, 0);
    }
    int c = ct * 16 + lr;
    float b = bias[c];
#pragma unroll
    for (int e = 0; e < 4; ++e) {
        int rr = rh * 16 + kq * 4 + e;
        int r = n0 + rr;
        if (r < N) {
            float v = fmaxf(acc[e] + b, 0.f);
            Hout[(size_t)r * NHID + c] = f2bf(v);
        }
    }
}

// Fused aggregate+GEMM+BN+segment-max (layer 3): same 32-node structure;
// epilogue applies bias+relu+BN, pre-reduces per-block segment max in LDS
// (32 sorted rows -> small span), then flushes encoded atomicMax.
__global__ __launch_bounds__(1024) void k_agg_gemm_bn(const unsigned int* __restrict__ Hin,
        const int* __restrict__ csr_src, const int* __restrict__ rowptr,
        const int* __restrict__ bsum, const int* __restrict__ cnt,
        const float* __restrict__ dinv, const unsigned short* __restrict__ Wt,
        const float* __restrict__ bias, const int* __restrict__ batch,
        const float* __restrict__ gamma, const float* __restrict__ beta,
        const float* __restrict__ rmean, const float* __restrict__ rvar,
        unsigned int* __restrict__ keys, int N) {
    __shared__ unsigned int lds[32][68];
    __shared__ unsigned int smax[32][NHID];   // 16 KB, indexed by local segment
    __shared__ int bseg[32];
    int tid = threadIdx.x;
    int wv = tid >> 6;
    int lane = tid & 63;
    int g = lane >> 4;
    int l16 = lane & 15;
    int n0 = blockIdx.x * 32;
    for (int i = tid; i < 32 * NHID; i += 1024) ((unsigned int*)smax)[i] = 0u;
    if (tid < 32) {
        int r = n0 + tid;
        bseg[tid] = batch[r < N ? r : N - 1];
    }
    gather_row(Hin, csr_src, rowptr, bsum, cnt, dinv, lds, n0 + 2 * wv,     2 * wv,     g, l16, N);
    gather_row(Hin, csr_src, rowptr, bsum, cnt, dinv, lds, n0 + 2 * wv + 1, 2 * wv + 1, g, l16, N);
    __syncthreads();   // lds rows + smax init + bseg ready
    int rh = wv >> 3;
    int ct = wv & 7;
    int lr = l16;
    int kq = g;
    f32x4 acc = {0.f, 0.f, 0.f, 0.f};
#pragma unroll
    for (int kg = 0; kg < 4; ++kg) {
        bf16x8 af = *reinterpret_cast<const bf16x8*>(&lds[rh * 16 + lr][kg * 16 + kq * 4]);
        bf16x8 bf = *reinterpret_cast<const bf16x8*>(
            Wt + (size_t)(ct * 16 + lr) * NHID + kg * 32 + kq * 8);
        acc = __builtin_amdgcn_mfma_f32_16x16x32_bf16(af, bf, acc, 0, 0, 0);
    }
    int c = ct * 16 + lr;
    float b = bias[c];
    float sc = gamma[c] * rsqrtf(rvar[c] + 1e-5f);
    float sh = beta[c] - rmean[c] * sc;
    int glo = bseg[0];
#pragma unroll
    for (int e = 0; e < 4; ++e) {
        int rr = rh * 16 + kq * 4 + e;
        if (n0 + rr < N) {
            float v = fmaxf(acc[e] + b, 0.f);
            float y = fmaf(v, sc, sh);
            atomicMax(&smax[bseg[rr] - glo][c], fenc(y));
        }
    }
    __syncthreads();
    int last = N - 1 - n0;
    if (last > 31) last = 31;
    int span = bseg[last] - glo + 1;
    for (int i = tid; i < span * NHID; i += 1024) {
        unsigned int v = ((unsigned int*)smax)[i];
        if (v) atomicMax(&keys[(size_t)(glo + (i >> 7)) * NHID + (i & 127)], v);
    }
}

// fused head: decode keys -> relu(G@lw1+lb1) -> relu(@lw2+lb2) -> @lw3+lb3
__global__ __launch_bounds__(128) void k_head(const unsigned int* __restrict__ keys,
        const float* __restrict__ lw1, const float* __restrict__ lb1,
        const float* __restrict__ lw2, const float* __restrict__ lb2,
        const float* __restrict__ lw3, const float* __restrict__ lb3,
        float* __restrict__ out) {
    __shared__ float g0[NHID], g1[NHID], g2[64];
    int r = blockIdx.x;
    int t = threadIdx.x;
    unsigned int u = keys[(size_t)r * NHID + t];
    g0[t] = (u == 0u) ? -3.0e38f : fdec(u);
    __syncthreads();
    float acc = lb1[t];
#pragma unroll 8
    for (int k = 0; k < NHID; ++k) acc = fmaf(g0[k], lw1[k * NHID + t], acc);
    g1[t] = fmaxf(acc, 0.f);
    __syncthreads();
    if (t < 64) {
        acc = lb2[t];
#pragma unroll 8
        for (int k = 0; k < NHID; ++k) acc = fmaf(g1[k], lw2[k * 64 + t], acc);
        g2[t] = fmaxf(acc, 0.f);
    }
    __syncthreads();
    if (t < NCLS) {
        acc = lb3[t];
#pragma unroll 8
        for (int k = 0; k < 64; ++k) acc = fmaf(g2[k], lw3[k * NCLS + t], acc);
        out[(size_t)r * NCLS + t] = acc;
    }
}

extern "C" void kernel_launch(void* const* d_in, const int* in_sizes, int n_in,
                              void* d_out, int out_size, void* d_ws, size_t ws_size,
                              hipStream_t stream) {
    const float* x     = (const float*)d_in[0];
    const int*   ei    = (const int*)d_in[1];
    const int*   batch = (const int*)d_in[2];
    const float* W1 = (const float*)d_in[3];
    const float* b1 = (const float*)d_in[4];
    const float* W2 = (const float*)d_in[5];
    const float* b2 = (const float*)d_in[6];
    const float* W3 = (const float*)d_in[7];
    const float* b3 = (const float*)d_in[8];
    const float* gamma = (const float*)d_in[9];
    const float* beta  = (const float*)d_in[10];
    const float* rmean = (const float*)d_in[11];
    const float* rvar  = (const float*)d_in[12];
    const float* lw1 = (const float*)d_in[13];
    const float* lb1 = (const float*)d_in[14];
    const float* lw2 = (const float*)d_in[15];
    const float* lb2 = (const float*)d_in[16];
    const float* lw3 = (const float*)d_in[17];
    const float* lb3 = (const float*)d_in[18];

    const int N = in_sizes[2];
    const int E = in_sizes[1] / 2;
    const int* src = ei;
    const int* dst = ei + E;

    char* ws = (char*)d_ws;
    size_t off = 0;
    auto alloc = [&](size_t bytes) {
        char* p = ws + off;
        off += (bytes + 255) & ~(size_t)255;
        return p;
    };
    int*   cnt     = (int*)  alloc((size_t)N * 8);     // cnt[N] + cursor[N], one memset
    int*   cursor  = cnt + N;
    int*   rowptr  = (int*)  alloc((size_t)N * 4);
    int*   bsum    = (int*)  alloc(1024 * 4);
    float* dinv    = (float*)alloc((size_t)N * 4);
    int*   csr_src = (int*)  alloc((size_t)E * 4);
    unsigned int* xb   = (unsigned int*)alloc((size_t)N * NHID * 2);
    unsigned int* Hb   = (unsigned int*)alloc((size_t)N * NHID * 2);
    unsigned int* H2   = (unsigned int*)alloc((size_t)N * NHID * 2);
    unsigned short* Wt = (unsigned short*)alloc((size_t)3 * NHID * NHID * 2);
    unsigned int* keys = (unsigned int*)alloc((size_t)NGRAPH * NHID * 4);
    (void)ws_size; (void)n_in; (void)out_size;

    hipMemsetAsync(cnt, 0, (size_t)N * 8, stream);

    int degB = (E + 255) / 256;
    int n8 = N * 16;
    int xB = (n8 + 255) / 256;
    int frontB = degB + xB + 192 + (NGRAPH * NHID + 255) / 256;
    k_front<<<frontB, 256, 0, stream>>>(dst, cnt, E, degB, x, xb, n8, xB,
                                        W1, W2, W3, Wt, keys);
    int nb1 = (N + 1023) / 1024;
    k_scan1<<<nb1, 1024, 0, stream>>>(cnt, dinv, rowptr, bsum, N);
    k_scan2<<<1, 1024, 0, stream>>>(bsum, nb1);
    k_fill<<<degB, 256, 0, stream>>>(src, dst, rowptr, bsum, cursor, csr_src, E);

    int fgb = (N + 31) / 32;                 // fused blocks (32 nodes each)
    // layer 1: xb -> Hb
    k_agg_gemm<<<fgb, 1024, 0, stream>>>(xb, csr_src, rowptr, bsum, cnt, dinv,
                                         Wt, b1, (unsigned short*)Hb, N);
    // layer 2: Hb -> H2
    k_agg_gemm<<<fgb, 1024, 0, stream>>>(Hb, csr_src, rowptr, bsum, cnt, dinv,
                                         Wt + 16384, b2, (unsigned short*)H2, N);
    // layer 3 fused: H2 -> keys (gemm+bn+segmax)
    k_agg_gemm_bn<<<fgb, 1024, 0, stream>>>(H2, csr_src, rowptr, bsum, cnt, dinv,
                                            Wt + 32768, b3, batch, gamma, beta,
                                            rmean, rvar, keys, N);

    k_head<<<NGRAPH, 128, 0, stream>>>(keys, lw1, lb1, lw2, lb2, lw3, lb3, (float*)d_out);
}